// Round 7
// baseline (94.420 us; speedup 1.0000x reference)
//
#include <hip/hip_runtime.h>
#include <hip/hip_bf16.h>

#define EPSW 1e-6f

typedef __attribute__((ext_vector_type(4))) float floatx4;
typedef __attribute__((ext_vector_type(4))) unsigned int uintx4;
typedef __attribute__((ext_vector_type(8))) short shortx8;   // 8 bf16 (4 VGPRs)

// round-to-nearest-even float -> bf16 bits (finite inputs)
__device__ __forceinline__ unsigned short f2bf(float f) {
    unsigned int u = __float_as_uint(f);
    u = (u + 0x7fffu + ((u >> 16) & 1u)) >> 16;
    return (unsigned short)u;
}

__device__ __forceinline__ unsigned int pk2(float lo, float hi) {
    return (unsigned int)f2bf(lo) | ((unsigned int)f2bf(hi) << 16);
}

// pack 8 fp32 -> bf16 MFMA fragment (shortx8)
__device__ __forceinline__ shortx8 pk8s(floatx4 a, floatx4 b) {
    union { uintx4 u; shortx8 s; } r;
    r.u.x = pk2(a.x, a.y); r.u.y = pk2(a.z, a.w);
    r.u.z = pk2(b.x, b.y); r.u.w = pk2(b.z, b.w);
    return r.s;
}

// ---------------------------------------------------------------------------
// gemm_mt: 260 blocks x 256 threads (4 waves).
//   blocks 0..255  : ZERO-LDS, ZERO-BARRIER register GEMM.
//                    ks = bid&7 (K-slice of 256; round-robin dispatch
//                    clusters same-ks blocks on one XCD -> W slice stays in
//                    that XCD's L2), rtile = bid>>3 (rows rtile*64..+63).
//   blocks 256..259: Mt[c][n] = (A@A)[n][c], 16 n-rows per block
//                    (r5-proven 256-thread variant).
// Design: every MFMA fragment is loaded DIRECTLY from global into registers
// in fragment layout -- lane (m = lane&15, q = lane>>4) reads 2 x float4 at
// row*2000 + k(c,p,q), k = c*64 + (p*4+q)*8. Per wave, a fragment load is
// 16 rows x 128 B contiguous, all bytes consumed. A-frags (x rows) are
// wave-private; B-frags (W h-tiles {wave, wave+4}) are DISJOINT across the
// 4 waves, so LDS sharing would buy nothing: no LDS, no __syncthreads, no
// staging writes. fp32->bf16 convert in registers (pk8s). 1-chunk-ahead
// prefetch: 12 float4 loads (~12 KB/wave) in flight during each chunk's
// convert+MFMA; waves never couple, so HBM latency is hidden by wave- and
// ILP-level overlap instead of barriersed pipelining.
// Per chunk per wave: 12 loads + 12 pk8s + 16 MFMA. acc[4 rt][2 hh].
// Epilogue: fp32 partials to zp[ks][row][h] (unique owner, plain stores).
// ---------------------------------------------------------------------------
__global__ __launch_bounds__(256) void gemm_mt(
        const float* __restrict__ x,
        const float* __restrict__ W,
        const int* __restrict__ ei,
        const float* __restrict__ ew,
        float* __restrict__ zp,
        float* __restrict__ Mt) {
    __shared__ float sA[4224];   // used only by Mt blocks (A 4096 | deg | dinv)
    const int bid = blockIdx.x;
    const int t   = threadIdx.x;

    if (bid >= 256) {
        // ---- Mt = (A@A)^T build, n-slice [bm*16, bm*16+16) (r5-proven) ----
        const int bm = bid - 256;
        float* A    = sA;                      // 4096 f, A[n][k]
        float* deg  = A + 4096;
        float* dinv = deg + 64;
        if (t < 64) deg[t] = 1.0f;             // self-loop pre-added
        for (int i = t; i < 4096; i += 256) A[i] = 0.0f;
        __syncthreads();
        const int* srcp = ei;
        const int* dstp = ei + 4096;
#pragma unroll
        for (int i = 0; i < 16; ++i) {
            const int e = i * 256 + t;
            float w = ew[e];
            w = (w <= 0.0f) ? EPSW : w;
            atomicAdd(&deg[dstp[e]], w);
        }
        __syncthreads();
        if (t < 64) dinv[t] = 1.0f / sqrtf(deg[t]);
        __syncthreads();
#pragma unroll
        for (int i = 0; i < 16; ++i) {
            const int e = i * 256 + t;
            float w = ew[e];
            w = (w <= 0.0f) ? EPSW : w;
            const int s = srcp[e], d = dstp[e];
            atomicAdd(&A[d * 64 + s], dinv[s] * w * dinv[d]);
        }
        if (t < 64) atomicAdd(&A[t * 64 + t], dinv[t] * dinv[t]);
        __syncthreads();
        const int c  = t & 63;
        const int rr = t >> 6;                 // 0..3 (wave-uniform)
        float s0 = 0.f, s1 = 0.f, s2 = 0.f, s3 = 0.f;
#pragma unroll 8
        for (int k = 0; k < 64; ++k) {
            const float akc = A[k * 64 + c];
            const float* an = A + (bm * 16 + rr * 4) * 64 + k;
            s0 += an[0]   * akc;
            s1 += an[64]  * akc;
            s2 += an[128] * akc;
            s3 += an[192] * akc;
        }
        float* mo = Mt + c * 64 + bm * 16 + rr * 4;
        mo[0] = s0; mo[1] = s1; mo[2] = s2; mo[3] = s3;
        return;
    }

    // ---- GEMM blocks ------------------------------------------------------
    const int ks    = bid & 7;          // K-slice (XCD-clustered)
    const int rtile = bid >> 3;         // 0..31
    const int rbase = rtile * 64;
    const int kbase = ks * 256;

    const int wave = t >> 6, lane = t & 63;
    const int m = lane & 15, q = lane >> 4;

    // per-lane row base pointers (A: x rows; B: W h-rows)
    const float* xr[4];
    const float* wr[2];
#pragma unroll
    for (int rt = 0; rt < 4; ++rt)
        xr[rt] = x + (size_t)(rbase + rt * 16 + m) * 2000;
#pragma unroll
    for (int hh = 0; hh < 2; ++hh)
        wr[hh] = W + (size_t)((wave + hh * 4) * 16 + m) * 2000;

    floatx4 acc[4][2];
#pragma unroll
    for (int rt = 0; rt < 4; ++rt)
#pragma unroll
        for (int hh = 0; hh < 2; ++hh)
            acc[rt][hh] = (floatx4){0.f, 0.f, 0.f, 0.f};

    // staged fp32 fragments for one chunk (all indices compile-time)
    floatx4 fx[4][2][2];    // [rt][p][half]
    floatx4 fw[2][2][2];    // [hh][p][half]

#define LOADC(c)                                                              \
    {                                                                         \
        _Pragma("unroll")                                                     \
        for (int p_ = 0; p_ < 2; ++p_) {                                      \
            const int k_ = kbase + (c) * 64 + (p_ * 4 + q) * 8;               \
            if (k_ < 2000) {                                                  \
                _Pragma("unroll")                                             \
                for (int rt_ = 0; rt_ < 4; ++rt_) {                           \
                    fx[rt_][p_][0] = *(const floatx4*)(xr[rt_] + k_);         \
                    fx[rt_][p_][1] = *(const floatx4*)(xr[rt_] + k_ + 4);     \
                }                                                             \
                _Pragma("unroll")                                             \
                for (int hh_ = 0; hh_ < 2; ++hh_) {                           \
                    fw[hh_][p_][0] = *(const floatx4*)(wr[hh_] + k_);         \
                    fw[hh_][p_][1] = *(const floatx4*)(wr[hh_] + k_ + 4);     \
                }                                                             \
            } else {                                                          \
                _Pragma("unroll")                                             \
                for (int rt_ = 0; rt_ < 4; ++rt_)                             \
                    fx[rt_][p_][0] = fx[rt_][p_][1] =                         \
                        (floatx4){0.f, 0.f, 0.f, 0.f};                        \
                _Pragma("unroll")                                             \
                for (int hh_ = 0; hh_ < 2; ++hh_)                             \
                    fw[hh_][p_][0] = fw[hh_][p_][1] =                         \
                        (floatx4){0.f, 0.f, 0.f, 0.f};                        \
            }                                                                 \
        }                                                                     \
    }

    LOADC(0);
#pragma unroll
    for (int c = 0; c < 4; ++c) {
        // convert current chunk to bf16 fragments (waits on its loads)
        shortx8 af[4][2], bf[2][2];
#pragma unroll
        for (int p = 0; p < 2; ++p) {
#pragma unroll
            for (int rt = 0; rt < 4; ++rt)
                af[rt][p] = pk8s(fx[rt][p][0], fx[rt][p][1]);
#pragma unroll
            for (int hh = 0; hh < 2; ++hh)
                bf[hh][p] = pk8s(fw[hh][p][0], fw[hh][p][1]);
        }
        // issue next chunk's loads -- in flight during this chunk's MFMA
        if (c < 3) LOADC(c + 1);
#pragma unroll
        for (int p = 0; p < 2; ++p)
#pragma unroll
            for (int rt = 0; rt < 4; ++rt)
#pragma unroll
                for (int hh = 0; hh < 2; ++hh)
                    acc[rt][hh] = __builtin_amdgcn_mfma_f32_16x16x32_bf16(
                        af[rt][p], bf[hh][p], acc[rt][hh], 0, 0, 0);
    }
#undef LOADC

    // epilogue: partial z. C/D layout: row = q*4+v, col = m.
    float* zslice = zp + ((size_t)ks * 2048 + rbase) * 128;
#pragma unroll
    for (int rt = 0; rt < 4; ++rt)
#pragma unroll
        for (int hh = 0; hh < 2; ++hh) {
            const int h = (wave + hh * 4) * 16 + m;
#pragma unroll
            for (int v = 0; v < 4; ++v) {
                const int n = rt * 16 + q * 4 + v;
                zslice[n * 128 + h] = acc[rt][hh][v];
            }
        }
}

// ---------------------------------------------------------------------------
// apply_M: y[b][n][h] = bias[h] + sum_m M[n][m] * (sum_ks zp[ks][b*64+m][h])
// Grid (32 b, 8 h-chunks of 16) x 256 thr (r1-proven).
// ---------------------------------------------------------------------------
__global__ __launch_bounds__(256) void apply_M(const float* __restrict__ zp,
                                               const float* __restrict__ Mtg,
                                               const float* __restrict__ bias,
                                               float* __restrict__ y) {
    __shared__ float Ms[4096];
    __shared__ float zs[64][16];
    const int b  = blockIdx.x;
    const int hc = blockIdx.y;
    const int t  = threadIdx.x;
#pragma unroll
    for (int i = 0; i < 16; ++i) Ms[i * 256 + t] = Mtg[i * 256 + t];
#pragma unroll
    for (int i = 0; i < 4; ++i) {
        const int idx = i * 256 + t;
        const int mr = idx >> 4, hh = idx & 15;
        float s = 0.0f;
#pragma unroll
        for (int ks = 0; ks < 8; ++ks)
            s += zp[((size_t)ks * 2048 + b * 64 + mr) * 128 + hc * 16 + hh];
        zs[mr][hh] = s;
    }
    __syncthreads();
    const int h  = t & 15;
    const int n0 = (t >> 4) * 4;
    const float bv = bias[hc * 16 + h];
    float s0 = bv, s1 = bv, s2 = bv, s3 = bv;
#pragma unroll
    for (int mm = 0; mm < 64; ++mm) {
        const float zv = zs[mm][h];
        s0 += Ms[mm * 64 + n0 + 0] * zv;
        s1 += Ms[mm * 64 + n0 + 1] * zv;
        s2 += Ms[mm * 64 + n0 + 2] * zv;
        s3 += Ms[mm * 64 + n0 + 3] * zv;
    }
    float* yp = y + (size_t)b * 8192 + (size_t)n0 * 128 + hc * 16 + h;
    yp[0]   = s0;
    yp[128] = s1;
    yp[256] = s2;
    yp[384] = s3;
}

extern "C" void kernel_launch(void* const* d_in, const int* in_sizes, int n_in,
                              void* d_out, int out_size, void* d_ws, size_t ws_size,
                              hipStream_t stream) {
    const float* x    = (const float*)d_in[0];   // (2048, 2000) fp32 (flat view)
    const int*   ei   = (const int*)d_in[1];     // (2, 4096)
    const float* ew   = (const float*)d_in[2];   // (4096,)
    const float* W    = (const float*)d_in[3];   // (128, 2000) fp32
    const float* bias = (const float*)d_in[4];   // (128,)
    float* y = (float*)d_out;                    // (32, 64, 128) fp32

    float* zp = (float*)d_ws;                    // 8*2048*128 f (8 MB)
    float* Mt = zp + 2097152;                    // 4096 f

    gemm_mt<<<260, 256, 0, stream>>>(x, W, ei, ew, zp, Mt);
    apply_M<<<dim3(32, 8), 256, 0, stream>>>(zp, Mt, bias, y);
}